// Round 1
// baseline (1427.253 us; speedup 1.0000x reference)
//
#include <hip/hip_runtime.h>
#include <math.h>

#define N_TOK 8192
#define HID   8192
#define NG    16
#define NE    16

#define TM     256          // tokens per tile
#define KC     32           // K chunk staged in LDS
#define KSPLIT 16
#define KSLICE (HID / KSPLIT)   // 512

// ---- ws layout (bytes) ----
#define OFF_GLOG 0u                                    // double [N_TOK][NG]  1 MiB
#define OFF_MLOG (OFF_GLOG + N_TOK*NG*8)               // double [N_TOK][NE]  1 MiB
#define OFF_CNT  (OFF_MLOG + N_TOK*NE*8)               // int [16]
#define OFF_GSUM (OFF_CNT  + 64)                       // float [16]
#define OFF_ESUM (OFF_GSUM + 64)                       // float [16]
#define OFF_TOPG (OFF_ESUM + 64)                       // int [N_TOK]
#define OFF_BUCK (OFF_TOPG + N_TOK*4)                  // int [NG][N_TOK]
#define ZERO_BYTES OFF_TOPG                            // zero glog+mlog+cnt+sums

// ---------------- Tier-1 group GEMM: glog[t][g] += hid[t,:] . gw[g,:] ----------------
__global__ __launch_bounds__(256) void k_group_gemm(
    const float* __restrict__ hid, const float* __restrict__ gw,
    double* __restrict__ glog)
{
    __shared__ float As[KC][TM + 4];   // transposed: As[k][token], pad 4 keeps 16B align
    __shared__ float Ws[KC][NG + 4];   // Ws[k][g]
    const int tid = threadIdx.x;
    const int tq  = tid >> 2;          // token quad 0..63
    const int gq  = tid & 3;           // group quad 0..3
    const int tok_base = blockIdx.x * TM;
    const int k_base   = blockIdx.y * KSLICE;

    double acc[4][4] = {};
    for (int kb = 0; kb < KSLICE; kb += KC) {
        #pragma unroll
        for (int j = 0; j < 8; ++j) {                 // 2048 float4 / 256 thr
            int idx = tid + 256 * j;
            int row = idx >> 3;                       // 8 float4 per row
            int jj  = idx & 7;
            float4 v = *(const float4*)&hid[(size_t)(tok_base + row) * HID + (k_base + kb + 4*jj)];
            As[4*jj+0][row] = v.x;
            As[4*jj+1][row] = v.y;
            As[4*jj+2][row] = v.z;
            As[4*jj+3][row] = v.w;
        }
        if (tid < 128) {
            int g = tid >> 3, jj = tid & 7;
            float4 v = *(const float4*)&gw[(size_t)g * HID + (k_base + kb + 4*jj)];
            Ws[4*jj+0][g] = v.x;
            Ws[4*jj+1][g] = v.y;
            Ws[4*jj+2][g] = v.z;
            Ws[4*jj+3][g] = v.w;
        }
        __syncthreads();
        #pragma unroll
        for (int kk = 0; kk < KC; ++kk) {
            float4 a = *(const float4*)&As[kk][4*tq];
            float4 w = *(const float4*)&Ws[kk][4*gq];
            double ax=a.x, ay=a.y, az=a.z, aw=a.w;
            double wx=w.x, wy=w.y, wz=w.z, ww=w.w;
            acc[0][0] += ax*wx; acc[0][1] += ax*wy; acc[0][2] += ax*wz; acc[0][3] += ax*ww;
            acc[1][0] += ay*wx; acc[1][1] += ay*wy; acc[1][2] += ay*wz; acc[1][3] += ay*ww;
            acc[2][0] += az*wx; acc[2][1] += az*wy; acc[2][2] += az*wz; acc[2][3] += az*ww;
            acc[3][0] += aw*wx; acc[3][1] += aw*wy; acc[3][2] += aw*wz; acc[3][3] += aw*ww;
        }
        __syncthreads();
    }
    #pragma unroll
    for (int i = 0; i < 4; ++i) {
        int t = tok_base + 4*tq + i;
        #pragma unroll
        for (int j = 0; j < 4; ++j)
            unsafeAtomicAdd(&glog[t*NG + 4*gq + j], acc[i][j]);
    }
}

// ---------------- routing: softmax over 16, argmax, bucket, group-prob sums ----------------
__global__ __launch_bounds__(256) void k_route(
    const double* __restrict__ glog, int* __restrict__ cnt,
    int* __restrict__ buckets, int* __restrict__ topg, float* __restrict__ gsum)
{
    int t = blockIdx.x * 256 + threadIdx.x;
    float v[NG];
    #pragma unroll
    for (int g = 0; g < NG; ++g) v[g] = (float)glog[t*NG + g];
    float m = v[0];
    #pragma unroll
    for (int g = 1; g < NG; ++g) m = fmaxf(m, v[g]);
    float p[NG], s = 0.f;
    #pragma unroll
    for (int g = 0; g < NG; ++g) { p[g] = expf(v[g] - m); s += p[g]; }
    float inv = 1.f / s;
    #pragma unroll
    for (int g = 0; g < NG; ++g) p[g] *= inv;

    int gi = 0; float best = v[0];
    #pragma unroll
    for (int g = 1; g < NG; ++g) if (v[g] > best) { best = v[g]; gi = g; }  // first-max wins

    int lane = threadIdx.x & 63;
    #pragma unroll
    for (int g = 0; g < NG; ++g) {
        float x = p[g];
        #pragma unroll
        for (int off = 32; off > 0; off >>= 1) x += __shfl_down(x, off);
        if (lane == 0) unsafeAtomicAdd(&gsum[g], x);
    }
    topg[t] = gi;
    int pos = atomicAdd(&cnt[gi], 1);
    buckets[gi * N_TOK + pos] = t;
}

// ---------------- Tier-2 mini GEMM over bucketed tokens ----------------
__global__ __launch_bounds__(256) void k_mini_gemm(
    const float* __restrict__ hid, const float* __restrict__ mg,
    const int* __restrict__ cnt, const int* __restrict__ buckets,
    double* __restrict__ mlog)
{
    const int g    = blockIdx.z;
    const int tile = blockIdx.x;
    int n = cnt[g] - tile * TM;
    if (n <= 0) return;
    if (n > TM) n = TM;

    __shared__ int   rows[TM];
    __shared__ float As[KC][TM + 4];
    __shared__ float Ws[KC][NE + 4];
    const int tid = threadIdx.x;
    const int tq  = tid >> 2;
    const int gq  = tid & 3;
    const int k_base = blockIdx.y * KSLICE;

    rows[tid] = buckets[g * N_TOK + tile * TM + min(tid, n - 1)];  // clamp dup for tail
    __syncthreads();

    double acc[4][4] = {};
    for (int kb = 0; kb < KSLICE; kb += KC) {
        #pragma unroll
        for (int j = 0; j < 8; ++j) {
            int idx = tid + 256 * j;
            int row = idx >> 3;
            int jj  = idx & 7;
            float4 v = *(const float4*)&hid[(size_t)rows[row] * HID + (k_base + kb + 4*jj)];
            As[4*jj+0][row] = v.x;
            As[4*jj+1][row] = v.y;
            As[4*jj+2][row] = v.z;
            As[4*jj+3][row] = v.w;
        }
        if (tid < 128) {
            // mini_gates[g][k][e]: k-major, e contiguous -> straight copy
            int kk = tid >> 2, e0 = (tid & 3) * 4;
            float4 v = *(const float4*)&mg[((size_t)g * HID + k_base + kb + kk) * NE + e0];
            *(float4*)&Ws[kk][e0] = v;
        }
        __syncthreads();
        #pragma unroll
        for (int kk = 0; kk < KC; ++kk) {
            float4 a = *(const float4*)&As[kk][4*tq];
            float4 w = *(const float4*)&Ws[kk][4*gq];
            double ax=a.x, ay=a.y, az=a.z, aw=a.w;
            double wx=w.x, wy=w.y, wz=w.z, ww=w.w;
            acc[0][0] += ax*wx; acc[0][1] += ax*wy; acc[0][2] += ax*wz; acc[0][3] += ax*ww;
            acc[1][0] += ay*wx; acc[1][1] += ay*wy; acc[1][2] += ay*wz; acc[1][3] += ay*ww;
            acc[2][0] += az*wx; acc[2][1] += az*wy; acc[2][2] += az*wz; acc[2][3] += az*ww;
            acc[3][0] += aw*wx; acc[3][1] += aw*wy; acc[3][2] += aw*wz; acc[3][3] += aw*ww;
        }
        __syncthreads();
    }
    #pragma unroll
    for (int i = 0; i < 4; ++i) {
        int tl = 4*tq + i;
        if (tl < n) {
            int t = rows[tl];
            #pragma unroll
            for (int j = 0; j < 4; ++j)
                unsafeAtomicAdd(&mlog[t*NE + 4*gq + j], acc[i][j]);
        }
    }
}

// ---------------- finalize: mini softmax, top-4, outputs, expert-prob sums ----------------
__global__ __launch_bounds__(256) void k_final(
    const double* __restrict__ mlog, const int* __restrict__ topg,
    float* __restrict__ out, float* __restrict__ esum)
{
    int t = blockIdx.x * 256 + threadIdx.x;
    float v[NE];
    #pragma unroll
    for (int e = 0; e < NE; ++e) v[e] = (float)mlog[t*NE + e];
    float m = v[0];
    #pragma unroll
    for (int e = 1; e < NE; ++e) m = fmaxf(m, v[e]);
    float p[NE], s = 0.f;
    #pragma unroll
    for (int e = 0; e < NE; ++e) { p[e] = expf(v[e] - m); s += p[e]; }
    float inv = 1.f / s;
    #pragma unroll
    for (int e = 0; e < NE; ++e) p[e] *= inv;

    int lane = threadIdx.x & 63;
    #pragma unroll
    for (int e = 0; e < NE; ++e) {
        float x = p[e];
        #pragma unroll
        for (int off = 32; off > 0; off >>= 1) x += __shfl_down(x, off);
        if (lane == 0) unsafeAtomicAdd(&esum[e], x);
    }

    unsigned used = 0;
    float tv[4]; int ti[4];
    #pragma unroll
    for (int j = 0; j < 4; ++j) {
        float best = -1.f; int bi = 0;
        #pragma unroll
        for (int e = 0; e < NE; ++e)
            if (!((used >> e) & 1u) && p[e] > best) { best = p[e]; bi = e; }
        used |= 1u << bi; tv[j] = best; ti[j] = bi;
    }
    float inv4 = 1.f / (tv[0] + tv[1] + tv[2] + tv[3]);  // top_group_prob cancels in normalization
    int g = topg[t];
    #pragma unroll
    for (int j = 0; j < 4; ++j) {
        out[t*4 + j]             = tv[j] * inv4;
        out[N_TOK*4 + t*4 + j]   = (float)(g * NE + ti[j]);
    }
}

// ---------------- aux loss scalar ----------------
__global__ void k_aux(const float* __restrict__ gsum, const float* __restrict__ esum,
                      float* __restrict__ out)
{
    if (threadIdx.x == 0) {
        float a = 0.f;
        for (int g = 0; g < NG; ++g) { float m = gsum[g] * (1.f / N_TOK); a += m * m; }
        for (int e = 0; e < NE; ++e) { float m = esum[e] * (1.f / N_TOK); a += m * m; }
        out[N_TOK * 8] = a;   // element 65536
    }
}

extern "C" void kernel_launch(void* const* d_in, const int* in_sizes, int n_in,
                              void* d_out, int out_size, void* d_ws, size_t ws_size,
                              hipStream_t stream) {
    const float* hid = (const float*)d_in[0];   // [8192,8192]
    const float* gw  = (const float*)d_in[1];   // [16,8192]
    const float* mg  = (const float*)d_in[2];   // [16,8192,16]
    float* out = (float*)d_out;
    char*  ws  = (char*)d_ws;
    double* glog   = (double*)(ws + OFF_GLOG);
    double* mlog   = (double*)(ws + OFF_MLOG);
    int*   cnt     = (int*)  (ws + OFF_CNT);
    float* gsum    = (float*)(ws + OFF_GSUM);
    float* esum    = (float*)(ws + OFF_ESUM);
    int*   topg    = (int*)  (ws + OFF_TOPG);
    int*   buckets = (int*)  (ws + OFF_BUCK);

    hipMemsetAsync(d_ws, 0, ZERO_BYTES, stream);

    k_group_gemm<<<dim3(N_TOK / TM, KSPLIT), 256, 0, stream>>>(hid, gw, glog);
    k_route<<<N_TOK / 256, 256, 0, stream>>>(glog, cnt, buckets, topg, gsum);
    k_mini_gemm<<<dim3(N_TOK / TM, KSPLIT, NG), 256, 0, stream>>>(hid, mg, cnt, buckets, mlog);
    k_final<<<N_TOK / 256, 256, 0, stream>>>(mlog, topg, out, esum);
    k_aux<<<1, 64, 0, stream>>>(gsum, esum, out);
}

// Round 2
// 740.044 us; speedup vs baseline: 1.9286x; 1.9286x over previous
//
#include <hip/hip_runtime.h>
#include <math.h>

#define N_TOK 8192
#define HID   8192
#define NG    16
#define NE    16
#define KC    512              // K per chunk
#define NCHUNK (HID / KC)      // 16
#define TPB   8                // tokens per block
#define WROW  (KC + 4)         // 516: LDS row stride in floats (16B-aligned rows)

// ---- ws layout (bytes) ----
#define OFF_CNT   0u
#define OFF_GSUM  64u
#define OFF_ESUM  128u
#define OFF_NTIL  192u
#define ZERO_BYTES 256u
#define OFF_GLOG  256u                               // double[8192][16]  1 MiB
#define OFF_MLOG  (OFF_GLOG + N_TOK*NG*8)            // double[8192][16]  1 MiB
#define OFF_TOPG  (OFF_MLOG + N_TOK*NE*8)            // int[8192]
#define OFF_BUCK  (OFF_TOPG + N_TOK*4)               // int[16][8192]
#define OFF_SCHED (OFF_BUCK + NG*N_TOK*4)            // int[2048]

// cross-lane f64 reduce-scatter round: halves the live acc count.
// lane-bit o decides which half this lane keeps; partner (lane^o) keeps the other.
#define RS_ROUND(o, half)                                                 \
  {                                                                       \
    const bool hi_ = (lane & (o)) != 0;                                   \
    _Pragma("unroll")                                                     \
    for (int i_ = 0; i_ < (half); ++i_) {                                 \
      double s_ = hi_ ? acc64[i_] : acc64[i_ + (half)];                   \
      double r_ = __shfl_xor(s_, (o));                                    \
      acc64[i_] = (hi_ ? acc64[i_ + (half)] : acc64[i_]) + r_;            \
    }                                                                     \
  }

// ---------------- Tier-1: glog[t][g] = hid[t,:] . gw[g,:]  (full K per block) ------------
__global__ __launch_bounds__(256, 2) void k_group(
    const float* __restrict__ hid, const float* __restrict__ gw,
    double* __restrict__ glog)
{
    __shared__ float W[NG][WROW];
    const int tid  = threadIdx.x;
    const int lane = tid & 63;
    const int wv   = tid >> 6;                    // wave 0..3
    const int t0   = blockIdx.x * TPB + wv * 2;   // this wave's 2 tokens
    const float* __restrict__ a0 = hid + (size_t)t0 * HID;
    const float* __restrict__ a1 = a0 + HID;

    float4 wreg[8];      // W prefetch: j = tid + 256*i -> g=j>>7, kq=j&127
    float4 areg[4];      // A prefetch: [t0 it0, t0 it1, t1 it0, t1 it1]

    #pragma unroll
    for (int i = 0; i < 8; ++i) {
        int j = tid + 256 * i;
        wreg[i] = *(const float4*)&gw[(size_t)(j >> 7) * HID + 4 * (j & 127)];
    }
    {
        int ka = 4 * lane;
        areg[0] = *(const float4*)&a0[ka];
        areg[1] = *(const float4*)&a0[ka + 256];
        areg[2] = *(const float4*)&a1[ka];
        areg[3] = *(const float4*)&a1[ka + 256];
    }

    double acc64[32];
    #pragma unroll
    for (int i = 0; i < 32; ++i) acc64[i] = 0.0;

    for (int c = 0; c < NCHUNK; ++c) {
        __syncthreads();                          // all waves done reading W(c-1)
        #pragma unroll
        for (int i = 0; i < 8; ++i) {             // stage W(c): contiguous b128 writes
            int j = tid + 256 * i;
            *(float4*)&W[j >> 7][4 * (j & 127)] = wreg[i];
        }
        __syncthreads();

        float4 aC[4];
        #pragma unroll
        for (int i = 0; i < 4; ++i) aC[i] = areg[i];

        if (c + 1 < NCHUNK) {                     // prefetch chunk c+1 (hidden under compute)
            int kb = (c + 1) * KC;
            #pragma unroll
            for (int i = 0; i < 8; ++i) {
                int j = tid + 256 * i;
                wreg[i] = *(const float4*)&gw[(size_t)(j >> 7) * HID + kb + 4 * (j & 127)];
            }
            int ka = kb + 4 * lane;
            areg[0] = *(const float4*)&a0[ka];
            areg[1] = *(const float4*)&a0[ka + 256];
            areg[2] = *(const float4*)&a1[ka];
            areg[3] = *(const float4*)&a1[ka + 256];
        }

        float acc32[32];
        #pragma unroll
        for (int i = 0; i < 32; ++i) acc32[i] = 0.f;
        #pragma unroll
        for (int g = 0; g < NG; ++g) {
            float4 w0 = *(const float4*)&W[g][4 * lane];         // conflict-free b128
            float4 w1 = *(const float4*)&W[g][256 + 4 * lane];
            acc32[g]      += aC[0].x*w0.x + aC[0].y*w0.y + aC[0].z*w0.z + aC[0].w*w0.w
                           + aC[1].x*w1.x + aC[1].y*w1.y + aC[1].z*w1.z + aC[1].w*w1.w;
            acc32[16 + g] += aC[2].x*w0.x + aC[2].y*w0.y + aC[2].z*w0.z + aC[2].w*w0.w
                           + aC[3].x*w1.x + aC[3].y*w1.y + aC[3].z*w1.z + aC[3].w*w1.w;
        }
        #pragma unroll
        for (int i = 0; i < 32; ++i) acc64[i] += (double)acc32[i];   // f64 flush (8 terms/chunk in fp32)
    }

    // 64-lane reduce: acc index a = t*16+g; lane ends with (t=lane bit4, g=lane&15)
    #pragma unroll
    for (int i = 0; i < 32; ++i) acc64[i] += __shfl_xor(acc64[i], 32);
    RS_ROUND(16, 16) RS_ROUND(8, 8) RS_ROUND(4, 4) RS_ROUND(2, 2) RS_ROUND(1, 1)
    if (lane < 32)
        glog[(size_t)(t0 + (lane >> 4)) * NG + (lane & 15)] = acc64[0];
}

// ---------------- routing: softmax/argmax over 16, bucket, group-prob sums ----------------
__global__ __launch_bounds__(64) void k_route(
    const double* __restrict__ glog, int* __restrict__ cnt,
    int* __restrict__ buckets, int* __restrict__ topg, float* __restrict__ gsum)
{
    int t = blockIdx.x * 64 + threadIdx.x;
    float v[NG];
    #pragma unroll
    for (int g = 0; g < NG; ++g) v[g] = (float)glog[t * NG + g];
    float m = v[0];
    #pragma unroll
    for (int g = 1; g < NG; ++g) m = fmaxf(m, v[g]);
    float p[NG], s = 0.f;
    #pragma unroll
    for (int g = 0; g < NG; ++g) { p[g] = expf(v[g] - m); s += p[g]; }
    float inv = 1.f / s;
    #pragma unroll
    for (int g = 0; g < NG; ++g) p[g] *= inv;

    int gi = 0; float best = v[0];
    #pragma unroll
    for (int g = 1; g < NG; ++g) if (v[g] > best) { best = v[g]; gi = g; }

    int lane = threadIdx.x & 63;
    #pragma unroll
    for (int g = 0; g < NG; ++g) {
        float x = p[g];
        #pragma unroll
        for (int off = 32; off > 0; off >>= 1) x += __shfl_down(x, off);
        if (lane == 0) unsafeAtomicAdd(&gsum[g], x);
    }
    topg[t] = gi;
    int pos = atomicAdd(&cnt[gi], 1);
    buckets[gi * N_TOK + pos] = t;
}

// ---------------- build compact (group,tile) worklist ----------------
__global__ void k_sched(const int* __restrict__ cnt, int* __restrict__ sched,
                        int* __restrict__ ntile)
{
    __shared__ int pref[NG + 1];
    if (threadIdx.x == 0) {
        int s = 0;
        for (int g = 0; g < NG; ++g) { pref[g] = s; s += (cnt[g] + TPB - 1) / TPB; }
        pref[NG] = s; *ntile = s;
    }
    __syncthreads();
    int total = pref[NG];
    for (int i = threadIdx.x; i < total; i += blockDim.x) {
        int g = 0;
        while (g < NG - 1 && i >= pref[g + 1]) ++g;
        sched[i] = (g << 16) | (i - pref[g]);
    }
}

// ---------------- Tier-2: mini logits for each token's selected group ----------------
__global__ __launch_bounds__(256, 2) void k_mini(
    const float* __restrict__ hid, const float* __restrict__ mg,
    const int* __restrict__ cnt, const int* __restrict__ buckets,
    const int* __restrict__ sched, const int* __restrict__ ntile,
    double* __restrict__ mlog)
{
    if ((int)blockIdx.x >= *ntile) return;
    const int enc  = sched[blockIdx.x];
    const int g    = enc >> 16;
    const int tile = enc & 0xffff;
    const int n    = cnt[g] - tile * TPB;         // 1..8 valid tokens

    __shared__ float W[NE][WROW];
    __shared__ int rows[TPB];
    const int tid  = threadIdx.x;
    const int lane = tid & 63;
    const int wv   = tid >> 6;

    if (tid < TPB)
        rows[tid] = buckets[g * N_TOK + tile * TPB + min(tid, n - 1)];  // clamp tail
    __syncthreads();
    const float* __restrict__ a0 = hid + (size_t)rows[wv * 2]     * HID;
    const float* __restrict__ a1 = hid + (size_t)rows[wv * 2 + 1] * HID;
    const float* __restrict__ wg = mg + (size_t)g * HID * NE;

    float4 wreg[8];     // j = tid+256*i -> k=j>>2 (0..511), q=j&3 (e-quad)
    float4 areg[4];
    #pragma unroll
    for (int i = 0; i < 8; ++i) {
        int j = tid + 256 * i;
        wreg[i] = *(const float4*)&wg[(size_t)(j >> 2) * NE + 4 * (j & 3)];
    }
    {
        int ka = 4 * lane;
        areg[0] = *(const float4*)&a0[ka];
        areg[1] = *(const float4*)&a0[ka + 256];
        areg[2] = *(const float4*)&a1[ka];
        areg[3] = *(const float4*)&a1[ka + 256];
    }

    double acc64[32];
    #pragma unroll
    for (int i = 0; i < 32; ++i) acc64[i] = 0.0;

    for (int c = 0; c < NCHUNK; ++c) {
        __syncthreads();
        #pragma unroll
        for (int i = 0; i < 8; ++i) {             // transpose-stage: [k][e] -> W[e][k]
            int j = tid + 256 * i;
            int k = j >> 2, e0 = 4 * (j & 3);
            W[e0 + 0][k] = wreg[i].x;
            W[e0 + 1][k] = wreg[i].y;
            W[e0 + 2][k] = wreg[i].z;
            W[e0 + 3][k] = wreg[i].w;
        }
        __syncthreads();

        float4 aC[4];
        #pragma unroll
        for (int i = 0; i < 4; ++i) aC[i] = areg[i];

        if (c + 1 < NCHUNK) {
            size_t kb = (size_t)(c + 1) * KC;
            #pragma unroll
            for (int i = 0; i < 8; ++i) {
                int j = tid + 256 * i;
                wreg[i] = *(const float4*)&wg[(kb + (j >> 2)) * NE + 4 * (j & 3)];
            }
            int ka = (int)kb + 4 * lane;
            areg[0] = *(const float4*)&a0[ka];
            areg[1] = *(const float4*)&a0[ka + 256];
            areg[2] = *(const float4*)&a1[ka];
            areg[3] = *(const float4*)&a1[ka + 256];
        }

        float acc32[32];
        #pragma unroll
        for (int i = 0; i < 32; ++i) acc32[i] = 0.f;
        #pragma unroll
        for (int e = 0; e < NE; ++e) {
            float4 w0 = *(const float4*)&W[e][4 * lane];
            float4 w1 = *(const float4*)&W[e][256 + 4 * lane];
            acc32[e]      += aC[0].x*w0.x + aC[0].y*w0.y + aC[0].z*w0.z + aC[0].w*w0.w
                           + aC[1].x*w1.x + aC[1].y*w1.y + aC[1].z*w1.z + aC[1].w*w1.w;
            acc32[16 + e] += aC[2].x*w0.x + aC[2].y*w0.y + aC[2].z*w0.z + aC[2].w*w0.w
                           + aC[3].x*w1.x + aC[3].y*w1.y + aC[3].z*w1.z + aC[3].w*w1.w;
        }
        #pragma unroll
        for (int i = 0; i < 32; ++i) acc64[i] += (double)acc32[i];
    }

    #pragma unroll
    for (int i = 0; i < 32; ++i) acc64[i] += __shfl_xor(acc64[i], 32);
    RS_ROUND(16, 16) RS_ROUND(8, 8) RS_ROUND(4, 4) RS_ROUND(2, 2) RS_ROUND(1, 1)
    if (lane < 32) {
        int tl = wv * 2 + (lane >> 4);
        if (tl < n)
            mlog[(size_t)rows[tl] * NE + (lane & 15)] = acc64[0];
    }
}

// ---------------- finalize: mini softmax, top-4, outputs, expert-prob sums ----------------
__global__ __launch_bounds__(64) void k_final(
    const double* __restrict__ mlog, const int* __restrict__ topg,
    float* __restrict__ out, float* __restrict__ esum)
{
    int t = blockIdx.x * 64 + threadIdx.x;
    float v[NE];
    #pragma unroll
    for (int e = 0; e < NE; ++e) v[e] = (float)mlog[t * NE + e];
    float m = v[0];
    #pragma unroll
    for (int e = 1; e < NE; ++e) m = fmaxf(m, v[e]);
    float p[NE], s = 0.f;
    #pragma unroll
    for (int e = 0; e < NE; ++e) { p[e] = expf(v[e] - m); s += p[e]; }
    float inv = 1.f / s;
    #pragma unroll
    for (int e = 0; e < NE; ++e) p[e] *= inv;

    int lane = threadIdx.x & 63;
    #pragma unroll
    for (int e = 0; e < NE; ++e) {
        float x = p[e];
        #pragma unroll
        for (int off = 32; off > 0; off >>= 1) x += __shfl_down(x, off);
        if (lane == 0) unsafeAtomicAdd(&esum[e], x);
    }

    unsigned used = 0;
    float tv[4]; int ti[4];
    #pragma unroll
    for (int j = 0; j < 4; ++j) {
        float best = -1.f; int bi = 0;
        #pragma unroll
        for (int e = 0; e < NE; ++e)
            if (!((used >> e) & 1u) && p[e] > best) { best = p[e]; bi = e; }
        used |= 1u << bi; tv[j] = best; ti[j] = bi;
    }
    float inv4 = 1.f / (tv[0] + tv[1] + tv[2] + tv[3]);  // top_group_prob cancels
    int g = topg[t];
    #pragma unroll
    for (int j = 0; j < 4; ++j) {
        out[t * 4 + j]           = tv[j] * inv4;
        out[N_TOK * 4 + t * 4 + j] = (float)(g * NE + ti[j]);
    }
}

// ---------------- aux loss scalar ----------------
__global__ void k_aux(const float* __restrict__ gsum, const float* __restrict__ esum,
                      float* __restrict__ out)
{
    if (threadIdx.x == 0) {
        float a = 0.f;
        for (int g = 0; g < NG; ++g) { float m = gsum[g] * (1.f / N_TOK); a += m * m; }
        for (int e = 0; e < NE; ++e) { float m = esum[e] * (1.f / N_TOK); a += m * m; }
        out[N_TOK * 8] = a;   // element 65536
    }
}

extern "C" void kernel_launch(void* const* d_in, const int* in_sizes, int n_in,
                              void* d_out, int out_size, void* d_ws, size_t ws_size,
                              hipStream_t stream) {
    const float* hid = (const float*)d_in[0];   // [8192,8192]
    const float* gw  = (const float*)d_in[1];   // [16,8192]
    const float* mg  = (const float*)d_in[2];   // [16,8192,16]
    float* out = (float*)d_out;
    char*  ws  = (char*)d_ws;
    int*    cnt     = (int*)   (ws + OFF_CNT);
    float*  gsum    = (float*) (ws + OFF_GSUM);
    float*  esum    = (float*) (ws + OFF_ESUM);
    int*    ntile   = (int*)   (ws + OFF_NTIL);
    double* glog    = (double*)(ws + OFF_GLOG);
    double* mlog    = (double*)(ws + OFF_MLOG);
    int*    topg    = (int*)   (ws + OFF_TOPG);
    int*    buckets = (int*)   (ws + OFF_BUCK);
    int*    sched   = (int*)   (ws + OFF_SCHED);

    hipMemsetAsync(d_ws, 0, ZERO_BYTES, stream);

    k_group<<<N_TOK / TPB, 256, 0, stream>>>(hid, gw, glog);
    k_route<<<N_TOK / 64, 64, 0, stream>>>(glog, cnt, buckets, topg, gsum);
    k_sched<<<1, 256, 0, stream>>>(cnt, sched, ntile);
    k_mini<<<N_TOK / TPB + NG, 256, 0, stream>>>(hid, mg, cnt, buckets, sched, ntile, mlog);
    k_final<<<N_TOK / 64, 64, 0, stream>>>(mlog, topg, out, esum);
    k_aux<<<1, 64, 0, stream>>>(gsum, esum, out);
}

// Round 3
// 574.503 us; speedup vs baseline: 2.4843x; 1.2881x over previous
//
#include <hip/hip_runtime.h>
#include <math.h>

#define N_TOK 8192
#define HID   8192
#define NG    16
#define NE    16
#define KC    512              // K per chunk
#define NCHUNK (HID / KC)      // 16
#define TPB   8                // tokens per block (2 per wave)

// ---- ws layout (bytes) ----
#define OFF_CNT   0u
#define OFF_GSUM  64u
#define OFF_ESUM  128u
#define OFF_NTIL  192u
#define ZERO_BYTES 256u
#define OFF_GLOG  256u                               // double[8192][16]  1 MiB
#define OFF_MLOG  (OFF_GLOG + N_TOK*NG*8)            // double[8192][16]  1 MiB
#define OFF_TOPG  (OFF_MLOG + N_TOK*NE*8)            // int[8192]
#define OFF_BUCK  (OFF_TOPG + N_TOK*4)               // int[16][8192]
#define OFF_SCHED (OFF_BUCK + NG*N_TOK*4)            // int[2048]
#define OFF_MGT   (OFF_SCHED + 2048*4)               // float[16][16][8192] 16 MiB

// global -> LDS DMA, 16B per lane; LDS dest = uniform base + lane*16
__device__ __forceinline__ void glds16(const float* gp, float* lp) {
    __builtin_amdgcn_global_load_lds(
        (const __attribute__((address_space(1))) void*)gp,
        (__attribute__((address_space(3))) void*)lp, 16, 0, 0);
}

// cross-lane f64 reduce-scatter round: halves live acc count
#define RS_ROUND(o, half)                                                 \
  {                                                                       \
    const bool hi_ = (lane & (o)) != 0;                                   \
    _Pragma("unroll")                                                     \
    for (int i_ = 0; i_ < (half); ++i_) {                                 \
      double s_ = hi_ ? acc64[i_] : acc64[i_ + (half)];                   \
      double r_ = __shfl_xor(s_, (o));                                    \
      acc64[i_] = (hi_ ? acc64[i_ + (half)] : acc64[i_]) + r_;            \
    }                                                                     \
  }

// ---------------- Tier-1: glog[t][g] = hid[t,:] . gw[g,:] ----------------
__global__ __launch_bounds__(256, 2) void k_group(
    const float* __restrict__ hid, const float* __restrict__ gw,
    double* __restrict__ glog)
{
    __shared__ float Wl[2][NG * KC];                 // 2 x 32 KB, no pad (contiguous for DMA)
    const int tid  = threadIdx.x;
    const int lane = tid & 63;
    const int wv   = tid >> 6;
    const int t0   = blockIdx.x * TPB + wv * 2;
    const float* __restrict__ a0 = hid + (size_t)t0 * HID;
    const float* __restrict__ a1 = a0 + HID;

    // issue W chunk0 -> buf0 (8 DMA instrs per wave; instr m covers floats m*256..)
    #pragma unroll
    for (int j = 0; j < 8; ++j) {
        int m = wv * 8 + j;                          // g = m>>1, half = m&1
        glds16(gw + (size_t)(m >> 1) * HID + (m & 1) * 256 + 4 * lane,
               &Wl[0][m * 256]);
    }
    float4 areg[4];
    areg[0] = *(const float4*)&a0[4 * lane];
    areg[1] = *(const float4*)&a0[256 + 4 * lane];
    areg[2] = *(const float4*)&a1[4 * lane];
    areg[3] = *(const float4*)&a1[256 + 4 * lane];

    double acc64[32];
    #pragma unroll
    for (int i = 0; i < 32; ++i) acc64[i] = 0.0;

    for (int c = 0; c < NCHUNK; ++c) {
        __syncthreads();                             // drains DMA: Wl[c&1] ready; reads of other buf done
        float4 aC0 = areg[0], aC1 = areg[1], aC2 = areg[2], aC3 = areg[3];
        if (c + 1 < NCHUNK) {                        // prefetch chunk c+1
            const int kb = (c + 1) * KC;
            #pragma unroll
            for (int j = 0; j < 8; ++j) {
                int m = wv * 8 + j;
                glds16(gw + (size_t)(m >> 1) * HID + kb + (m & 1) * 256 + 4 * lane,
                       &Wl[(c + 1) & 1][m * 256]);
            }
            areg[0] = *(const float4*)&a0[kb + 4 * lane];
            areg[1] = *(const float4*)&a0[kb + 256 + 4 * lane];
            areg[2] = *(const float4*)&a1[kb + 4 * lane];
            areg[3] = *(const float4*)&a1[kb + 256 + 4 * lane];
        }
        const float* Wc = &Wl[c & 1][0];
        #pragma unroll
        for (int g = 0; g < NG; ++g) {
            float4 w0 = *(const float4*)&Wc[g * KC + 4 * lane];        // contiguous b128
            float4 w1 = *(const float4*)&Wc[g * KC + 256 + 4 * lane];
            float d0 = aC0.x*w0.x + aC0.y*w0.y + aC0.z*w0.z + aC0.w*w0.w
                     + aC1.x*w1.x + aC1.y*w1.y + aC1.z*w1.z + aC1.w*w1.w;
            float d1 = aC2.x*w0.x + aC2.y*w0.y + aC2.z*w0.z + aC2.w*w0.w
                     + aC3.x*w1.x + aC3.y*w1.y + aC3.z*w1.z + aC3.w*w1.w;
            acc64[g]      += (double)d0;             // fp32 sums only 8 terms before f64
            acc64[16 + g] += (double)d1;
        }
    }

    #pragma unroll
    for (int i = 0; i < 32; ++i) acc64[i] += __shfl_xor(acc64[i], 32);
    RS_ROUND(16, 16) RS_ROUND(8, 8) RS_ROUND(4, 4) RS_ROUND(2, 2) RS_ROUND(1, 1)
    if (lane < 32)
        glog[(size_t)(t0 + (lane >> 4)) * NG + (lane & 15)] = acc64[0];
}

// ---------------- mg [g][k][e] -> mgT [g][e][k] (one-shot, L2 absorbs strided reads) ----
__global__ __launch_bounds__(256) void k_tr(
    const float* __restrict__ mg, float* __restrict__ mgT)
{
    int id = blockIdx.x * 256 + threadIdx.x;         // 16*16*2048 threads
    int g  = id >> 15;
    int r  = id & 32767;
    int e  = r >> 11;
    int kq = r & 2047;
    const float* src = mg + (size_t)g * HID * NE + (size_t)(4 * kq) * NE + e;
    float4 v;
    v.x = src[0]; v.y = src[NE]; v.z = src[2 * NE]; v.w = src[3 * NE];
    *(float4*)&mgT[(size_t)(g * NE + e) * HID + 4 * kq] = v;   // coalesced writes
}

// ---------------- routing: softmax/argmax over 16, bucket, group-prob sums ----------------
__global__ __launch_bounds__(64) void k_route(
    const double* __restrict__ glog, int* __restrict__ cnt,
    int* __restrict__ buckets, int* __restrict__ topg, float* __restrict__ gsum)
{
    int t = blockIdx.x * 64 + threadIdx.x;
    float v[NG];
    #pragma unroll
    for (int g = 0; g < NG; ++g) v[g] = (float)glog[t * NG + g];
    float m = v[0];
    #pragma unroll
    for (int g = 1; g < NG; ++g) m = fmaxf(m, v[g]);
    float p[NG], s = 0.f;
    #pragma unroll
    for (int g = 0; g < NG; ++g) { p[g] = expf(v[g] - m); s += p[g]; }
    float inv = 1.f / s;
    #pragma unroll
    for (int g = 0; g < NG; ++g) p[g] *= inv;

    int gi = 0; float best = v[0];
    #pragma unroll
    for (int g = 1; g < NG; ++g) if (v[g] > best) { best = v[g]; gi = g; }

    int lane = threadIdx.x & 63;
    #pragma unroll
    for (int g = 0; g < NG; ++g) {
        float x = p[g];
        #pragma unroll
        for (int off = 32; off > 0; off >>= 1) x += __shfl_down(x, off);
        if (lane == 0) unsafeAtomicAdd(&gsum[g], x);
    }
    topg[t] = gi;
    int pos = atomicAdd(&cnt[gi], 1);
    buckets[gi * N_TOK + pos] = t;
}

// ---------------- build compact (group,tile) worklist ----------------
__global__ void k_sched(const int* __restrict__ cnt, int* __restrict__ sched,
                        int* __restrict__ ntile)
{
    __shared__ int pref[NG + 1];
    if (threadIdx.x == 0) {
        int s = 0;
        for (int g = 0; g < NG; ++g) { pref[g] = s; s += (cnt[g] + TPB - 1) / TPB; }
        pref[NG] = s; *ntile = s;
    }
    __syncthreads();
    int total = pref[NG];
    for (int i = threadIdx.x; i < total; i += blockDim.x) {
        int g = 0;
        while (g < NG - 1 && i >= pref[g + 1]) ++g;
        sched[i] = (g << 16) | (i - pref[g]);
    }
}

// ---------------- Tier-2: mini logits, structurally == k_group via mgT ----------------
__global__ __launch_bounds__(256, 2) void k_mini(
    const float* __restrict__ hid, const float* __restrict__ mgT,
    const int* __restrict__ cnt, const int* __restrict__ buckets,
    const int* __restrict__ sched, const int* __restrict__ ntile,
    double* __restrict__ mlog)
{
    if ((int)blockIdx.x >= *ntile) return;
    const int enc  = sched[blockIdx.x];
    const int g    = enc >> 16;
    const int tile = enc & 0xffff;
    const int n    = cnt[g] - tile * TPB;            // 1..8 valid tokens

    __shared__ float Wl[2][NE * KC];
    __shared__ int rows[TPB];
    const int tid  = threadIdx.x;
    const int lane = tid & 63;
    const int wv   = tid >> 6;

    if (tid < TPB)
        rows[tid] = buckets[g * N_TOK + tile * TPB + min(tid, n - 1)];  // clamp tail (dup ok)
    __syncthreads();
    const float* __restrict__ a0 = hid + (size_t)rows[wv * 2]     * HID;
    const float* __restrict__ a1 = hid + (size_t)rows[wv * 2 + 1] * HID;
    const float* __restrict__ wg = mgT + (size_t)g * NE * HID;

    #pragma unroll
    for (int j = 0; j < 8; ++j) {
        int m = wv * 8 + j;                          // e = m>>1, half = m&1
        glds16(wg + (size_t)(m >> 1) * HID + (m & 1) * 256 + 4 * lane,
               &Wl[0][m * 256]);
    }
    float4 areg[4];
    areg[0] = *(const float4*)&a0[4 * lane];
    areg[1] = *(const float4*)&a0[256 + 4 * lane];
    areg[2] = *(const float4*)&a1[4 * lane];
    areg[3] = *(const float4*)&a1[256 + 4 * lane];

    double acc64[32];
    #pragma unroll
    for (int i = 0; i < 32; ++i) acc64[i] = 0.0;

    for (int c = 0; c < NCHUNK; ++c) {
        __syncthreads();
        float4 aC0 = areg[0], aC1 = areg[1], aC2 = areg[2], aC3 = areg[3];
        if (c + 1 < NCHUNK) {
            const int kb = (c + 1) * KC;
            #pragma unroll
            for (int j = 0; j < 8; ++j) {
                int m = wv * 8 + j;
                glds16(wg + (size_t)(m >> 1) * HID + kb + (m & 1) * 256 + 4 * lane,
                       &Wl[(c + 1) & 1][m * 256]);
            }
            areg[0] = *(const float4*)&a0[kb + 4 * lane];
            areg[1] = *(const float4*)&a0[kb + 256 + 4 * lane];
            areg[2] = *(const float4*)&a1[kb + 4 * lane];
            areg[3] = *(const float4*)&a1[kb + 256 + 4 * lane];
        }
        const float* Wc = &Wl[c & 1][0];
        #pragma unroll
        for (int e = 0; e < NE; ++e) {
            float4 w0 = *(const float4*)&Wc[e * KC + 4 * lane];
            float4 w1 = *(const float4*)&Wc[e * KC + 256 + 4 * lane];
            float d0 = aC0.x*w0.x + aC0.y*w0.y + aC0.z*w0.z + aC0.w*w0.w
                     + aC1.x*w1.x + aC1.y*w1.y + aC1.z*w1.z + aC1.w*w1.w;
            float d1 = aC2.x*w0.x + aC2.y*w0.y + aC2.z*w0.z + aC2.w*w0.w
                     + aC3.x*w1.x + aC3.y*w1.y + aC3.z*w1.z + aC3.w*w1.w;
            acc64[e]      += (double)d0;
            acc64[16 + e] += (double)d1;
        }
    }

    #pragma unroll
    for (int i = 0; i < 32; ++i) acc64[i] += __shfl_xor(acc64[i], 32);
    RS_ROUND(16, 16) RS_ROUND(8, 8) RS_ROUND(4, 4) RS_ROUND(2, 2) RS_ROUND(1, 1)
    if (lane < 32) {
        int tl = wv * 2 + (lane >> 4);
        if (tl < n)
            mlog[(size_t)rows[tl] * NE + (lane & 15)] = acc64[0];
    }
}

// ---------------- finalize: mini softmax, top-4, outputs, expert-prob sums ----------------
__global__ __launch_bounds__(64) void k_final(
    const double* __restrict__ mlog, const int* __restrict__ topg,
    float* __restrict__ out, float* __restrict__ esum)
{
    int t = blockIdx.x * 64 + threadIdx.x;
    float v[NE];
    #pragma unroll
    for (int e = 0; e < NE; ++e) v[e] = (float)mlog[t * NE + e];
    float m = v[0];
    #pragma unroll
    for (int e = 1; e < NE; ++e) m = fmaxf(m, v[e]);
    float p[NE], s = 0.f;
    #pragma unroll
    for (int e = 0; e < NE; ++e) { p[e] = expf(v[e] - m); s += p[e]; }
    float inv = 1.f / s;
    #pragma unroll
    for (int e = 0; e < NE; ++e) p[e] *= inv;

    int lane = threadIdx.x & 63;
    #pragma unroll
    for (int e = 0; e < NE; ++e) {
        float x = p[e];
        #pragma unroll
        for (int off = 32; off > 0; off >>= 1) x += __shfl_down(x, off);
        if (lane == 0) unsafeAtomicAdd(&esum[e], x);
    }

    unsigned used = 0;
    float tv[4]; int ti[4];
    #pragma unroll
    for (int j = 0; j < 4; ++j) {
        float best = -1.f; int bi = 0;
        #pragma unroll
        for (int e = 0; e < NE; ++e)
            if (!((used >> e) & 1u) && p[e] > best) { best = p[e]; bi = e; }
        used |= 1u << bi; tv[j] = best; ti[j] = bi;
    }
    float inv4 = 1.f / (tv[0] + tv[1] + tv[2] + tv[3]);  // top_group_prob cancels
    int g = topg[t];
    #pragma unroll
    for (int j = 0; j < 4; ++j) {
        out[t * 4 + j]             = tv[j] * inv4;
        out[N_TOK * 4 + t * 4 + j] = (float)(g * NE + ti[j]);
    }
}

// ---------------- aux loss scalar ----------------
__global__ void k_aux(const float* __restrict__ gsum, const float* __restrict__ esum,
                      float* __restrict__ out)
{
    if (threadIdx.x == 0) {
        float a = 0.f;
        for (int g = 0; g < NG; ++g) { float m = gsum[g] * (1.f / N_TOK); a += m * m; }
        for (int e = 0; e < NE; ++e) { float m = esum[e] * (1.f / N_TOK); a += m * m; }
        out[N_TOK * 8] = a;   // element 65536
    }
}

extern "C" void kernel_launch(void* const* d_in, const int* in_sizes, int n_in,
                              void* d_out, int out_size, void* d_ws, size_t ws_size,
                              hipStream_t stream) {
    const float* hid = (const float*)d_in[0];   // [8192,8192]
    const float* gw  = (const float*)d_in[1];   // [16,8192]
    const float* mg  = (const float*)d_in[2];   // [16,8192,16]
    float* out = (float*)d_out;
    char*  ws  = (char*)d_ws;
    int*    cnt     = (int*)   (ws + OFF_CNT);
    float*  gsum    = (float*) (ws + OFF_GSUM);
    float*  esum    = (float*) (ws + OFF_ESUM);
    int*    ntile   = (int*)   (ws + OFF_NTIL);
    double* glog    = (double*)(ws + OFF_GLOG);
    double* mlog    = (double*)(ws + OFF_MLOG);
    int*    topg    = (int*)   (ws + OFF_TOPG);
    int*    buckets = (int*)   (ws + OFF_BUCK);
    int*    sched   = (int*)   (ws + OFF_SCHED);
    float*  mgT     = (float*) (ws + OFF_MGT);

    hipMemsetAsync(d_ws, 0, ZERO_BYTES, stream);

    k_tr<<<2048, 256, 0, stream>>>(mg, mgT);
    k_group<<<N_TOK / TPB, 256, 0, stream>>>(hid, gw, glog);
    k_route<<<N_TOK / 64, 64, 0, stream>>>(glog, cnt, buckets, topg, gsum);
    k_sched<<<1, 256, 0, stream>>>(cnt, sched, ntile);
    k_mini<<<N_TOK / TPB + NG, 256, 0, stream>>>(hid, mgT, cnt, buckets, sched, ntile, mlog);
    k_final<<<N_TOK / 64, 64, 0, stream>>>(mlog, topg, out, esum);
    k_aux<<<1, 64, 0, stream>>>(gsum, esum, out);
}

// Round 5
// 537.524 us; speedup vs baseline: 2.6552x; 1.0688x over previous
//
#include <hip/hip_runtime.h>
#include <math.h>

#define N_TOK 8192
#define HID   8192
#define NG    16
#define NE    16
#define KC    512              // K per chunk
#define NCHUNK (HID / KC)      // 16
#define TPB   16               // tokens per block (4 per wave)

// ---- ws layout (bytes) ----
#define OFF_CNT   0u
#define OFF_GSUM  64u
#define OFF_ESUM  128u
#define OFF_NTIL  192u
#define ZERO_BYTES 256u
#define OFF_BUCK  256u                               // int[16][8192]
#define OFF_SCHED (OFF_BUCK + NG*N_TOK*4)            // int[2048]
#define OFF_MGT   (OFF_SCHED + 2048*4)               // float[16][16][8192] 16 MiB

// global -> LDS DMA, 16B per lane; LDS dest = uniform base + lane*16
__device__ __forceinline__ void glds16(const float* gp, float* lp) {
    __builtin_amdgcn_global_load_lds(
        (const __attribute__((address_space(1))) void*)gp,
        (__attribute__((address_space(3))) void*)lp, 16, 0, 0);
}

// cross-lane f64 reduce-scatter round: halves live acc count.
// After rounds (32..1), lane L holds original acc index L.
#define RS_ROUND(o, half)                                                 \
  {                                                                       \
    const bool hi_ = (lane & (o)) != 0;                                   \
    _Pragma("unroll")                                                     \
    for (int i_ = 0; i_ < (half); ++i_) {                                 \
      double s_ = hi_ ? acc64[i_] : acc64[i_ + (half)];                   \
      double r_ = __shfl_xor(s_, (o));                                    \
      acc64[i_] = (hi_ ? acc64[i_ + (half)] : acc64[i_]) + r_;            \
    }                                                                     \
  }

#define DOT8(t, w0, w1)                                                   \
    (aC[2*(t)].x*(w0).x + aC[2*(t)].y*(w0).y + aC[2*(t)].z*(w0).z +       \
     aC[2*(t)].w*(w0).w + aC[2*(t)+1].x*(w1).x + aC[2*(t)+1].y*(w1).y +   \
     aC[2*(t)+1].z*(w1).z + aC[2*(t)+1].w*(w1).w)

// ---------------- Tier-1: group logits + fused softmax/argmax/bucket ----------------
__global__ __launch_bounds__(256, 2) void k_group(
    const float* __restrict__ hid, const float* __restrict__ gw,
    int* __restrict__ cnt, int* __restrict__ buckets, float* __restrict__ gsum)
{
    __shared__ float Wl[2][NG * KC];                 // 2 x 32 KB
    const int tid  = threadIdx.x;
    const int lane = tid & 63;
    const int wv   = tid >> 6;
    const int t0   = blockIdx.x * TPB + wv * 4;      // wave owns 4 tokens
    const float* __restrict__ a0 = hid + (size_t)t0 * HID;

    #pragma unroll
    for (int j = 0; j < 8; ++j) {                    // DMA W chunk0
        int m = wv * 8 + j;                          // g = m>>1, half = m&1
        glds16(gw + (size_t)(m >> 1) * HID + (m & 1) * 256 + 4 * lane,
               &Wl[0][m * 256]);
    }
    float4 areg[8];
    #pragma unroll
    for (int t = 0; t < 4; ++t) {
        areg[2*t]   = *(const float4*)&a0[(size_t)t * HID + 4 * lane];
        areg[2*t+1] = *(const float4*)&a0[(size_t)t * HID + 256 + 4 * lane];
    }

    double acc64[64];
    #pragma unroll
    for (int i = 0; i < 64; ++i) acc64[i] = 0.0;

    for (int c = 0; c < NCHUNK; ++c) {
        __syncthreads();                             // drains DMA(c) + a-loads(c)
        float4 aC[8];
        #pragma unroll
        for (int i = 0; i < 8; ++i) aC[i] = areg[i];
        if (c + 1 < NCHUNK) {
            const int kb = (c + 1) * KC;
            #pragma unroll
            for (int j = 0; j < 8; ++j) {
                int m = wv * 8 + j;
                glds16(gw + (size_t)(m >> 1) * HID + kb + (m & 1) * 256 + 4 * lane,
                       &Wl[(c + 1) & 1][m * 256]);
            }
            #pragma unroll
            for (int t = 0; t < 4; ++t) {
                areg[2*t]   = *(const float4*)&a0[(size_t)t * HID + kb + 4 * lane];
                areg[2*t+1] = *(const float4*)&a0[(size_t)t * HID + kb + 256 + 4 * lane];
            }
        }
        const float* Wc = &Wl[c & 1][0];
        #pragma unroll
        for (int g = 0; g < NG; ++g) {
            float4 w0 = *(const float4*)&Wc[g * KC + 4 * lane];
            float4 w1 = *(const float4*)&Wc[g * KC + 256 + 4 * lane];
            #pragma unroll
            for (int t = 0; t < 4; ++t)
                acc64[t * 16 + g] += (double)DOT8(t, w0, w1);   // fp32 only sums 8 terms
        }
    }

    RS_ROUND(32, 32) RS_ROUND(16, 16) RS_ROUND(8, 8)
    RS_ROUND(4, 4)   RS_ROUND(2, 2)   RS_ROUND(1, 1)
    // lane holds logit for (t = lane>>4, g = lane&15)
    float v = (float)acc64[0];
    float mx = v;
    #pragma unroll
    for (int o = 8; o; o >>= 1) mx = fmaxf(mx, __shfl_xor(mx, o));
    float p = expf(v - mx);
    float s = p;
    #pragma unroll
    for (int o = 8; o; o >>= 1) s += __shfl_xor(s, o);
    p /= s;
    float x = p;                                     // sum probs over wave's 4 tokens
    x += __shfl_xor(x, 16);
    x += __shfl_xor(x, 32);
    if (lane < 16) unsafeAtomicAdd(&gsum[lane], x);
    int gi = lane & 15; float bv = v;                // first-index-wins argmax on fp32
    #pragma unroll
    for (int o = 8; o; o >>= 1) {
        float ov = __shfl_xor(bv, o);
        int   og = __shfl_xor(gi, o);
        if (ov > bv || (ov == bv && og < gi)) { bv = ov; gi = og; }
    }
    if ((lane & 15) == 0) {
        int t = t0 + (lane >> 4);
        int pos = atomicAdd(&cnt[gi], 1);
        buckets[gi * N_TOK + pos] = t;
    }
}

// ---------------- mg [g][k][e] -> mgT [g][e][k], full K coverage ----------------
__global__ __launch_bounds__(256) void k_tr(
    const float* __restrict__ mg, float* __restrict__ mgT)
{
    const int g  = blockIdx.x >> 7;                  // 16 g x 128 k-blocks = 2048 blocks
    const int kb = (blockIdx.x & 127) * 64;          // 64 k per block -> covers k 0..8191
    const int e  = threadIdx.x & 15;
    const int kq = threadIdx.x >> 4;                 // 0..15
    const int k0 = kb + 4 * kq;
    const float* src = mg + (size_t)g * HID * NE;
    float4 v;
    v.x = src[(size_t)(k0 + 0) * NE + e];
    v.y = src[(size_t)(k0 + 1) * NE + e];
    v.z = src[(size_t)(k0 + 2) * NE + e];
    v.w = src[(size_t)(k0 + 3) * NE + e];
    *(float4*)&mgT[(size_t)(g * NE + e) * HID + k0] = v;   // coalesced writes
}

// ---------------- build compact (group,tile) worklist ----------------
__global__ void k_sched(const int* __restrict__ cnt, int* __restrict__ sched,
                        int* __restrict__ ntile)
{
    __shared__ int pref[NG + 1];
    if (threadIdx.x == 0) {
        int s = 0;
        for (int g = 0; g < NG; ++g) { pref[g] = s; s += (cnt[g] + TPB - 1) / TPB; }
        pref[NG] = s; *ntile = s;
    }
    __syncthreads();
    int total = pref[NG];
    for (int i = threadIdx.x; i < total; i += blockDim.x) {
        int g = 0;
        while (g < NG - 1 && i >= pref[g + 1]) ++g;
        sched[i] = (g << 16) | (i - pref[g]);
    }
}

// ---------------- Tier-2: mini logits + fused softmax/top-4/output ----------------
__global__ __launch_bounds__(256, 2) void k_mini(
    const float* __restrict__ hid, const float* __restrict__ mgT,
    const int* __restrict__ cnt, const int* __restrict__ buckets,
    const int* __restrict__ sched, const int* __restrict__ ntile,
    float* __restrict__ out, float* __restrict__ esum)
{
    if ((int)blockIdx.x >= *ntile) return;
    const int enc  = sched[blockIdx.x];
    const int g    = enc >> 16;
    const int tile = enc & 0xffff;
    const int n    = cnt[g] - tile * TPB;            // 1..16 valid tokens

    __shared__ float Wl[2][NE * KC];
    __shared__ int   rows[TPB];
    __shared__ float sm[256];
    const int tid  = threadIdx.x;
    const int lane = tid & 63;
    const int wv   = tid >> 6;
    const float* __restrict__ wg = mgT + (size_t)g * NE * HID;

    #pragma unroll
    for (int j = 0; j < 8; ++j) {                    // DMA W chunk0 (independent of rows)
        int m = wv * 8 + j;
        glds16(wg + (size_t)(m >> 1) * HID + (m & 1) * 256 + 4 * lane,
               &Wl[0][m * 256]);
    }
    if (tid < TPB)
        rows[tid] = buckets[g * N_TOK + tile * TPB + min(tid, n - 1)];  // clamp dup tail
    __syncthreads();
    const float* at[4];
    #pragma unroll
    for (int t = 0; t < 4; ++t) at[t] = hid + (size_t)rows[wv * 4 + t] * HID;

    float4 areg[8];
    #pragma unroll
    for (int t = 0; t < 4; ++t) {
        areg[2*t]   = *(const float4*)&at[t][4 * lane];
        areg[2*t+1] = *(const float4*)&at[t][256 + 4 * lane];
    }
    double acc64[64];
    #pragma unroll
    for (int i = 0; i < 64; ++i) acc64[i] = 0.0;

    for (int c = 0; c < NCHUNK; ++c) {
        __syncthreads();
        float4 aC[8];
        #pragma unroll
        for (int i = 0; i < 8; ++i) aC[i] = areg[i];
        if (c + 1 < NCHUNK) {
            const int kb = (c + 1) * KC;
            #pragma unroll
            for (int j = 0; j < 8; ++j) {
                int m = wv * 8 + j;
                glds16(wg + (size_t)(m >> 1) * HID + kb + (m & 1) * 256 + 4 * lane,
                       &Wl[(c + 1) & 1][m * 256]);
            }
            #pragma unroll
            for (int t = 0; t < 4; ++t) {
                areg[2*t]   = *(const float4*)&at[t][kb + 4 * lane];
                areg[2*t+1] = *(const float4*)&at[t][kb + 256 + 4 * lane];
            }
        }
        const float* Wc = &Wl[c & 1][0];
        #pragma unroll
        for (int e = 0; e < NE; ++e) {
            float4 w0 = *(const float4*)&Wc[e * KC + 4 * lane];
            float4 w1 = *(const float4*)&Wc[e * KC + 256 + 4 * lane];
            #pragma unroll
            for (int t = 0; t < 4; ++t)
                acc64[t * 16 + e] += (double)DOT8(t, w0, w1);
        }
    }

    RS_ROUND(32, 32) RS_ROUND(16, 16) RS_ROUND(8, 8)
    RS_ROUND(4, 4)   RS_ROUND(2, 2)   RS_ROUND(1, 1)
    // lane holds logit for (tl = wv*4 + (lane>>4), e = lane&15)
    const int tl = wv * 4 + (lane >> 4);
    float v = (float)acc64[0];
    float mx = v;
    #pragma unroll
    for (int o = 8; o; o >>= 1) mx = fmaxf(mx, __shfl_xor(mx, o));
    float p = expf(v - mx);
    float s = p;
    #pragma unroll
    for (int o = 8; o; o >>= 1) s += __shfl_xor(s, o);
    p /= s;
    float x = (tl < n) ? p : 0.f;                    // exclude dup-clamped tail tokens
    x += __shfl_xor(x, 16);
    x += __shfl_xor(x, 32);
    if (lane < 16) unsafeAtomicAdd(&esum[lane], x);

    sm[tid] = p;                                     // sm[tl*16 + e]
    __syncthreads();
    if ((tid & 15) == 0) {                           // leader per token
        int tt = tid >> 4;                           // == tl
        if (tt < n) {
            float pe[NE];
            #pragma unroll
            for (int e = 0; e < NE; ++e) pe[e] = sm[tt * 16 + e];
            unsigned used = 0;
            float tv[4]; int ti[4];
            #pragma unroll
            for (int j = 0; j < 4; ++j) {
                float best = -1.f; int bi = 0;
                #pragma unroll
                for (int e = 0; e < NE; ++e)
                    if (!((used >> e) & 1u) && pe[e] > best) { best = pe[e]; bi = e; }
                used |= 1u << bi; tv[j] = best; ti[j] = bi;
            }
            float inv4 = 1.f / (tv[0] + tv[1] + tv[2] + tv[3]);   // group prob cancels
            int t = rows[tt];
            #pragma unroll
            for (int j = 0; j < 4; ++j) {
                out[t * 4 + j]             = tv[j] * inv4;
                out[N_TOK * 4 + t * 4 + j] = (float)(g * NE + ti[j]);
            }
        }
    }
}

// ---------------- aux loss scalar ----------------
__global__ void k_aux(const float* __restrict__ gsum, const float* __restrict__ esum,
                      float* __restrict__ out)
{
    if (threadIdx.x == 0) {
        float a = 0.f;
        for (int g = 0; g < NG; ++g) { float m = gsum[g] * (1.f / N_TOK); a += m * m; }
        for (int e = 0; e < NE; ++e) { float m = esum[e] * (1.f / N_TOK); a += m * m; }
        out[N_TOK * 8] = a;   // element 65536
    }
}

extern "C" void kernel_launch(void* const* d_in, const int* in_sizes, int n_in,
                              void* d_out, int out_size, void* d_ws, size_t ws_size,
                              hipStream_t stream) {
    const float* hid = (const float*)d_in[0];   // [8192,8192]
    const float* gw  = (const float*)d_in[1];   // [16,8192]
    const float* mg  = (const float*)d_in[2];   // [16,8192,16]
    float* out = (float*)d_out;
    char*  ws  = (char*)d_ws;
    int*    cnt     = (int*)   (ws + OFF_CNT);
    float*  gsum    = (float*) (ws + OFF_GSUM);
    float*  esum    = (float*) (ws + OFF_ESUM);
    int*    ntile   = (int*)   (ws + OFF_NTIL);
    int*    buckets = (int*)   (ws + OFF_BUCK);
    int*    sched   = (int*)   (ws + OFF_SCHED);
    float*  mgT     = (float*) (ws + OFF_MGT);

    hipMemsetAsync(d_ws, 0, ZERO_BYTES, stream);

    k_tr<<<2048, 256, 0, stream>>>(mg, mgT);
    k_group<<<N_TOK / TPB, 256, 0, stream>>>(hid, gw, cnt, buckets, gsum);
    k_sched<<<1, 256, 0, stream>>>(cnt, sched, ntile);
    k_mini<<<N_TOK / TPB + NG, 256, 0, stream>>>(hid, mgT, cnt, buckets, sched, ntile, out, esum);
    k_aux<<<1, 64, 0, stream>>>(gsum, esum, out);
}